// Round 17
// baseline (295.136 us; speedup 1.0000x reference)
//
#include <hip/hip_runtime.h>
#include <hip/hip_bf16.h>
#include <math.h>

#define T_SEQ 2048
#define DMODEL 2048
#define NHQ 16
#define NHK 8
#define HDIM 128
#define NL 4
#define ATT_SCALE 0.08838834764831845f   // 1/sqrt(128)
#define SCALE2 0.12751649736383447f      // ATT_SCALE * log2(e)
#define THR2 11.541560327111707f         // 8 * log2(e)

typedef __attribute__((ext_vector_type(8))) short bf16x8;
typedef __attribute__((ext_vector_type(4))) float f32x4;

__device__ __forceinline__ float bf2f(short u) {
    union { float f; unsigned int i; } x;
    x.i = ((unsigned int)(unsigned short)u) << 16;
    return x.f;
}
__device__ __forceinline__ unsigned short f2bf(float f) {
    __hip_bfloat16 h = __float2bfloat16(f);
    return *reinterpret_cast<unsigned short*>(&h);
}
__device__ __forceinline__ float vexp2(float x) {      // 2^x, 1 inst
    float r;
    asm("v_exp_f32 %0, %1" : "=v"(r) : "v"(x));
    return r;
}
__device__ __forceinline__ unsigned int cvtpk(float lo, float hi) {  // lo->b16[0], hi->b16[1]
    unsigned int r;
    asm("v_cvt_pk_bf16_f32 %0, %1, %2" : "=v"(r) : "v"(lo), "v"(hi));
    return r;
}
__device__ __forceinline__ void gload16(const void* g, void* l) {
    __builtin_amdgcn_global_load_lds(
        (const __attribute__((address_space(1))) void*)g,
        (__attribute__((address_space(3))) void*)l, 16, 0, 0);
}

// ---------------------------------------------------------------------------
// Fused prep: x cast (blocks 0..2047) + 4 weight transpose-casts.
// ---------------------------------------------------------------------------
__global__ __launch_bounds__(256) void prep(
    const float* __restrict__ x, const float* __restrict__ Wq,
    const float* __restrict__ Wk, const float* __restrict__ Wv,
    const float* __restrict__ Wo,
    unsigned short* __restrict__ xb, unsigned short* __restrict__ WTp,
    unsigned short* __restrict__ WoT)
{
    __shared__ float ls[64][65];
    const int bid = blockIdx.x, tid = threadIdx.x;
    if (bid < 2048) {                      // ---- x cast ----
        int i = bid * 256 + tid;
        float4 a = ((const float4*)x)[2 * i];
        float4 b = ((const float4*)x)[2 * i + 1];
        bf16x8 v;
        v[0] = (short)f2bf(a.x); v[1] = (short)f2bf(a.y);
        v[2] = (short)f2bf(a.z); v[3] = (short)f2bf(a.w);
        v[4] = (short)f2bf(b.x); v[5] = (short)f2bf(b.y);
        v[6] = (short)f2bf(b.z); v[7] = (short)f2bf(b.w);
        ((bf16x8*)xb)[i] = v;
        return;
    }
    int v = bid - 2048;
    const float* src; unsigned short* dst; int Nsrc, dstOff, id;
    if (v < 1024)      { src = Wq; dst = WTp; Nsrc = 2048; dstOff = 0;    id = v; }
    else if (v < 1536) { src = Wk; dst = WTp; Nsrc = 1024; dstOff = 2048; id = v - 1024; }
    else if (v < 2048) { src = Wv; dst = WTp; Nsrc = 1024; dstOff = 3072; id = v - 1536; }
    else               { src = Wo; dst = WoT; Nsrc = 2048; dstOff = 0;    id = v - 2048; }
    const int k0 = (id & 31) * 64, n0 = (id >> 5) * 64;
    #pragma unroll
    for (int it = 0; it < 4; ++it) {
        int fi = tid + it * 256;
        int r = fi >> 4;
        int c = (fi & 15) * 4;
        float4 w = *(const float4*)&src[(size_t)(k0 + r) * Nsrc + n0 + c];
        ls[r][c] = w.x; ls[r][c + 1] = w.y; ls[r][c + 2] = w.z; ls[r][c + 3] = w.w;
    }
    __syncthreads();
    int n = tid & 63, kc = tid >> 6;
    bf16x8 v0, v1;
    #pragma unroll
    for (int j = 0; j < 8; ++j) v0[j] = (short)f2bf(ls[kc * 16 + j][n]);
    #pragma unroll
    for (int j = 0; j < 8; ++j) v1[j] = (short)f2bf(ls[kc * 16 + 8 + j][n]);
    size_t drow = (size_t)(dstOff + n0 + n) * 2048 + k0 + kc * 16;
    *(bf16x8*)&dst[drow] = v0;
    *(bf16x8*)&dst[drow + 8] = v1;
}

// ---------------------------------------------------------------------------
// bf16 MFMA GEMM, 128x64 tile (validated R8). mode 1: fused proj epilogue.
// ---------------------------------------------------------------------------
__global__ __launch_bounds__(256, 4) void gemm_bt(
    const unsigned short* __restrict__ A, const unsigned short* __restrict__ Bt,
    float* __restrict__ Cf, unsigned short* __restrict__ Cq,
    unsigned short* __restrict__ Ck, unsigned short* __restrict__ Cv,
    int mode, int K)
{
    __shared__ char As[16384];   // [128 m][64 k] bf16, chunk ^= row&7
    __shared__ char Bs[8192];    // [64 n][64 k] bf16, chunk ^= row&7
    const int tid = threadIdx.x;
    const int wv = tid >> 6, lane = tid & 63;
    const int l15 = lane & 15, lg = lane >> 4;
    const int wm = wv >> 1, wn = wv & 1;
    const int bm = blockIdx.y * 128, bn = blockIdx.x * 64;

    f32x4 acc[4][2];
    #pragma unroll
    for (int i = 0; i < 4; ++i)
        #pragma unroll
        for (int j = 0; j < 2; ++j)
            acc[i][j] = (f32x4){0.f, 0.f, 0.f, 0.f};

    for (int k0 = 0; k0 < K; k0 += 64) {
        #pragma unroll
        for (int it = 0; it < 4; ++it) {
            int o = it * 4096 + tid * 16;
            int row = o >> 7;
            int sch = ((o >> 4) & 7) ^ (row & 7);
            gload16((const char*)A + ((((size_t)(bm + row) * K) + k0 + sch * 8) << 1),
                    As + it * 4096 + wv * 1024);
        }
        #pragma unroll
        for (int it = 0; it < 2; ++it) {
            int o = it * 4096 + tid * 16;
            int row = o >> 7;
            int sch = ((o >> 4) & 7) ^ (row & 7);
            gload16((const char*)Bt + ((((size_t)(bn + row) * K) + k0 + sch * 8) << 1),
                    Bs + it * 4096 + wv * 1024);
        }
        __syncthreads();
        #pragma unroll
        for (int kk = 0; kk < 2; ++kk) {
            bf16x8 av[4], bv[2];
            #pragma unroll
            for (int f = 0; f < 4; ++f) {
                int ra = wm * 64 + f * 16 + l15;
                av[f] = *(const bf16x8*)(As + ra * 128 + ((((kk << 2) | lg) ^ (ra & 7)) << 4));
            }
            #pragma unroll
            for (int f = 0; f < 2; ++f) {
                int rb = wn * 32 + f * 16 + l15;
                bv[f] = *(const bf16x8*)(Bs + rb * 128 + ((((kk << 2) | lg) ^ (rb & 7)) << 4));
            }
            #pragma unroll
            for (int mf = 0; mf < 4; ++mf)
                #pragma unroll
                for (int nf = 0; nf < 2; ++nf)
                    acc[mf][nf] = __builtin_amdgcn_mfma_f32_16x16x32_bf16(
                        av[mf], bv[nf], acc[mf][nf], 0, 0, 0);
        }
        __syncthreads();
    }

    #pragma unroll
    for (int mf = 0; mf < 4; ++mf) {
        int m0 = bm + wm * 64 + mf * 16 + lg * 4;
        #pragma unroll
        for (int nf = 0; nf < 2; ++nf) {
            int n0 = bn + wn * 32 + nf * 16 + l15;
            if (mode == 0) {
                #pragma unroll
                for (int r = 0; r < 4; ++r)
                    Cf[(size_t)(m0 + r) * 2048 + n0] = acc[mf][nf][r];
            } else if (n0 < 2048) {
                #pragma unroll
                for (int r = 0; r < 4; ++r)
                    Cq[(size_t)(m0 + r) * 2048 + n0] = f2bf(acc[mf][nf][r]);
            } else if (n0 < 3072) {
                #pragma unroll
                for (int r = 0; r < 4; ++r)
                    Ck[(size_t)(m0 + r) * 1024 + (n0 - 2048)] = f2bf(acc[mf][nf][r]);
            } else {
                ushort4 u;
                u.x = f2bf(acc[mf][nf][0]); u.y = f2bf(acc[mf][nf][1]);
                u.z = f2bf(acc[mf][nf][2]); u.w = f2bf(acc[mf][nf][3]);
                *(ushort4*)&Cv[(size_t)(n0 - 3072) * 2048 + m0] = u;
            }
        }
    }
}

// ---------------------------------------------------------------------------
// bf16 MFMA GEMM, 64x64 tile, f32 C (Wo: grid 32x32 = 4 blocks/CU).
// ---------------------------------------------------------------------------
__global__ __launch_bounds__(256, 4) void gemm_bt64(
    const unsigned short* __restrict__ A, const unsigned short* __restrict__ Bt,
    float* __restrict__ Cf, int K)
{
    __shared__ char As[8192];    // [64 m][64 k] bf16, chunk ^= row&7
    __shared__ char Bs[8192];    // [64 n][64 k] bf16, chunk ^= row&7
    const int tid = threadIdx.x;
    const int wv = tid >> 6, lane = tid & 63;
    const int l15 = lane & 15, lg = lane >> 4;
    const int wm = wv >> 1, wn = wv & 1;
    const int bm = blockIdx.y * 64, bn = blockIdx.x * 64;

    f32x4 acc[2][2];
    #pragma unroll
    for (int i = 0; i < 2; ++i)
        #pragma unroll
        for (int j = 0; j < 2; ++j)
            acc[i][j] = (f32x4){0.f, 0.f, 0.f, 0.f};

    for (int k0 = 0; k0 < K; k0 += 64) {
        #pragma unroll
        for (int it = 0; it < 2; ++it) {
            int o = it * 4096 + tid * 16;
            int row = o >> 7;
            int sch = ((o >> 4) & 7) ^ (row & 7);
            gload16((const char*)A + ((((size_t)(bm + row) * K) + k0 + sch * 8) << 1),
                    As + it * 4096 + wv * 1024);
            gload16((const char*)Bt + ((((size_t)(bn + row) * K) + k0 + sch * 8) << 1),
                    Bs + it * 4096 + wv * 1024);
        }
        __syncthreads();
        #pragma unroll
        for (int kk = 0; kk < 2; ++kk) {
            bf16x8 av[2], bv[2];
            #pragma unroll
            for (int f = 0; f < 2; ++f) {
                int ra = wm * 32 + f * 16 + l15;
                av[f] = *(const bf16x8*)(As + ra * 128 + ((((kk << 2) | lg) ^ (ra & 7)) << 4));
                int rb = wn * 32 + f * 16 + l15;
                bv[f] = *(const bf16x8*)(Bs + rb * 128 + ((((kk << 2) | lg) ^ (rb & 7)) << 4));
            }
            #pragma unroll
            for (int mf = 0; mf < 2; ++mf)
                #pragma unroll
                for (int nf = 0; nf < 2; ++nf)
                    acc[mf][nf] = __builtin_amdgcn_mfma_f32_16x16x32_bf16(
                        av[mf], bv[nf], acc[mf][nf], 0, 0, 0);
        }
        __syncthreads();
    }

    #pragma unroll
    for (int mf = 0; mf < 2; ++mf) {
        int m0 = bm + wm * 32 + mf * 16 + lg * 4;
        #pragma unroll
        for (int nf = 0; nf < 2; ++nf) {
            int n0 = bn + wn * 32 + nf * 16 + l15;
            #pragma unroll
            for (int r = 0; r < 4; ++r)
                Cf[(size_t)(m0 + r) * 2048 + n0] = acc[mf][nf][r];
        }
    }
}

// ---------------------------------------------------------------------------
// Fused RoPE on Qb (H=16) and Kb (H=8), one dispatch.
// ---------------------------------------------------------------------------
__global__ __launch_bounds__(256) void rope2(
    unsigned short* __restrict__ Qb, unsigned short* __restrict__ Kb,
    const float* __restrict__ cosT, const float* __restrict__ sinT)
{
    int idx = blockIdx.x * 256 + threadIdx.x;
    unsigned short* P; int H;
    if (idx < T_SEQ * NHQ * 64) { P = Qb; H = NHQ; }
    else { idx -= T_SEQ * NHQ * 64; P = Kb; H = NHK; }
    int d = idx & 63;
    int h = (idx >> 6) % H;
    int t = idx / (64 * H);
    float c = cosT[t * HDIM + d];
    float s = sinT[t * HDIM + d];
    unsigned short* row = P + (size_t)t * (H * HDIM) + h * HDIM;
    float x0 = bf2f((short)row[d]), x1 = bf2f((short)row[d + 64]);
    row[d]      = f2bf(x0 * c - x1 * s);
    row[d + 64] = f2bf(x1 * c + x0 * s);
}

// ---------------------------------------------------------------------------
// Fused attention. R17: V moved from LDS staging to REGISTER prefetch (T14
// issue-early/use-late: 8x global_load_dwordx4 from L2 issued before QK^T,
// consumed after softmax). LDS 36KB -> 20KB => 5 blocks/CU
// (__launch_bounds__(256,5)); DS-pipe traffic per tile nearly halves.
// Depth blocks interleaved per R16 (group g%7<2), XCD-pinned.
// ---------------------------------------------------------------------------
__global__ __launch_bounds__(256, 5) void attn_fused(
    const unsigned short* __restrict__ Qb, const unsigned short* __restrict__ Kb,
    const unsigned short* __restrict__ Vt,
    const float* __restrict__ Dk, const float* __restrict__ Dv,
    unsigned short* __restrict__ Opart, float2* __restrict__ mlpart)
{
    __shared__ char Ks[2][8192];   // [32 keys][128 d] bf16, chunk ^= key&7
    __shared__ char Ps[4096];      // 4 waves x [16 q][32 keys] bf16

    const int bid0 = blockIdx.x;
    const int tid = threadIdx.x;
    const size_t DSTRIDE = (size_t)NHK * T_SEQ * HDIM;

    const int grp = bid0 >> 3, xcd = bid0 & 7;
    const int gm = grp % 7, gd = grp / 7;

    if (gm < 2) {
        // ================= depth partials (slot 4), interleaved =================
        const int hk = xcd;
        const int tc = gd * 2 + gm;             // 0..63
        const int row = tid >> 3;               // 0..31
        const int dp = tid & 7;                 // 16-d slice
        const int t = tc * 32 + row;
        const int qt = t >> 6, rowin = t & 63;
        const size_t base = ((size_t)hk * T_SEQ + t) * HDIM + dp * 16;

        float q[2][16];
        #pragma unroll
        for (int e = 0; e < 2; ++e) {
            const unsigned short* qp = Qb + (size_t)t * DMODEL + (hk * 2 + e) * HDIM + dp * 16;
            bf16x8 v0 = *(const bf16x8*)qp;
            bf16x8 v1 = *(const bf16x8*)(qp + 8);
            #pragma unroll
            for (int j = 0; j < 8; ++j) { q[e][j] = bf2f(v0[j]); q[e][8 + j] = bf2f(v1[j]); }
        }
        float dl[2][NL];
        #pragma unroll
        for (int l = 0; l < NL; ++l) {
            const float* kp = Dk + l * DSTRIDE + base;
            float a0 = 0.f, a1 = 0.f;
            #pragma unroll
            for (int c = 0; c < 4; ++c) {
                float4 k4 = *(const float4*)(kp + c * 4);
                a0 = fmaf(q[0][c*4+0], k4.x, a0); a0 = fmaf(q[0][c*4+1], k4.y, a0);
                a0 = fmaf(q[0][c*4+2], k4.z, a0); a0 = fmaf(q[0][c*4+3], k4.w, a0);
                a1 = fmaf(q[1][c*4+0], k4.x, a1); a1 = fmaf(q[1][c*4+1], k4.y, a1);
                a1 = fmaf(q[1][c*4+2], k4.z, a1); a1 = fmaf(q[1][c*4+3], k4.w, a1);
            }
            a0 += __shfl_xor(a0, 1); a0 += __shfl_xor(a0, 2); a0 += __shfl_xor(a0, 4);
            a1 += __shfl_xor(a1, 1); a1 += __shfl_xor(a1, 2); a1 += __shfl_xor(a1, 4);
            dl[0][l] = a0 * SCALE2;              // log2 domain
            dl[1][l] = a1 * SCALE2;
        }
        float m2[2], ls2[2], pd[2][NL];
        #pragma unroll
        for (int e = 0; e < 2; ++e) {
            m2[e] = fmaxf(fmaxf(dl[e][0], dl[e][1]), fmaxf(dl[e][2], dl[e][3]));
            ls2[e] = 0.f;
            #pragma unroll
            for (int l = 0; l < NL; ++l) { pd[e][l] = vexp2(dl[e][l] - m2[e]); ls2[e] += pd[e][l]; }
        }
        float o[2][16];
        #pragma unroll
        for (int e = 0; e < 2; ++e)
            #pragma unroll
            for (int j = 0; j < 16; ++j) o[e][j] = 0.f;
        #pragma unroll
        for (int l = 0; l < NL; ++l) {
            const float* vp = Dv + l * DSTRIDE + base;
            #pragma unroll
            for (int c = 0; c < 4; ++c) {
                float4 v4 = *(const float4*)(vp + c * 4);
                #pragma unroll
                for (int e = 0; e < 2; ++e) {
                    o[e][c*4+0] = fmaf(pd[e][l], v4.x, o[e][c*4+0]);
                    o[e][c*4+1] = fmaf(pd[e][l], v4.y, o[e][c*4+1]);
                    o[e][c*4+2] = fmaf(pd[e][l], v4.z, o[e][c*4+2]);
                    o[e][c*4+3] = fmaf(pd[e][l], v4.w, o[e][c*4+3]);
                }
            }
        }
        #pragma unroll
        for (int e = 0; e < 2; ++e) {
            int pidx = ((hk * 2 + e) * 32 + qt) * 5 + 4;
            unsigned short* dst = Opart + (size_t)pidx * 8192 + rowin * 128 + dp * 16;
            bf16x8 w0, w1;
            #pragma unroll
            for (int j = 0; j < 8; ++j) { w0[j] = (short)f2bf(o[e][j]); w1[j] = (short)f2bf(o[e][8 + j]); }
            *(bf16x8*)dst = w0;
            *(bf16x8*)(dst + 8) = w1;
            if (dp == 0) mlpart[pidx * 64 + rowin] = make_float2(m2[e], ls2[e]);
        }
        return;
    }

    // ================= seq split-K attention (interleaved) =================
    const int hk = xcd;
    const int idx = gd * 5 + (gm - 2);            // 0..159, rises with dispatch
    const int hq = hk * 2 + (idx & 1);
    const int si = 79 - (idx >> 1);               // long segments first
    int qt, seg;
    if (si < 8)       { qt = si;            seg = 0; }
    else if (si < 24) { int v = si - 8;  qt = 8  + (v >> 1); seg = v & 1; }
    else if (si < 48) { int v = si - 24; int q3 = v / 3; qt = 16 + q3; seg = v - q3 * 3; }
    else              { int v = si - 48; qt = 24 + (v >> 2); seg = v & 3; }
    const int q0 = qt * 64;
    const int jbeg = seg * 512;
    const int jend = min(jbeg + 512, q0 + 64);

    const int wv = tid >> 6, lane = tid & 63;
    const int l15 = lane & 15, lg = lane >> 4;

    const int tq = q0 + wv * 16 + l15;
    const int qmax = q0 + wv * 16 + 15;
    const int qmin = q0 + wv * 16;

    bf16x8 qf[4];
    {
        const unsigned short* qrow = Qb + (size_t)tq * DMODEL + hq * HDIM;
        #pragma unroll
        for (int c = 0; c < 4; ++c)
            qf[c] = *(const bf16x8*)(qrow + c * 32 + lg * 8);
    }

    // ---- hoisted lane-constant addressing ----
    const int kx = l15 & 7;
    const int koff0 = ((lg + 0)  ^ kx) << 4;
    const int koff1 = ((lg + 4)  ^ kx) << 4;
    const int koff2 = ((lg + 8)  ^ kx) << 4;
    const int koff3 = ((lg + 12) ^ kx) << 4;
    const int kbase = l15 * 256;
    const int w2  = (l15 >> 1) & 3;
    char* pw = Ps + wv * 1024;
    char* pwr0 = pw + l15 * 64 + (((lg >> 1) ^ w2) << 4) + (lg & 1) * 8;
    char* pwr1 = pw + l15 * 64 + ((((lg >> 1) + 2) ^ w2) << 4) + (lg & 1) * 8;
    const char* prd = pw + l15 * 64 + ((lg ^ w2) << 4);

    const int rk = tid >> 4, ckk = tid & 15;
    const size_t kc0 = (size_t)rk * 2048 + hk * 256 + ((size_t)(ckk ^ (rk & 7)) << 4);
    const char* KbB = (const char*)Kb;
    // V register-prefetch base: lane reads Vt[hk*128 + dt*16 + l15][j0 + lg*8 ..+7]
    const unsigned short* vbase = Vt + ((size_t)(hk * 128 + l15) * T_SEQ) + lg * 8;

    f32x4 oacc[8];
    #pragma unroll
    for (int dt = 0; dt < 8; ++dt) oacc[dt] = (f32x4){0.f, 0.f, 0.f, 0.f};
    float m = -1e30f, l = 0.f;               // m in log2 domain

    #define STAGE(J0, BUF)                                                      \
        {                                                                       \
            gload16(KbB + (size_t)(J0) * 2048 + kc0, Ks[BUF] + wv * 1024);      \
            gload16(KbB + (size_t)(J0) * 2048 + kc0 + 32768,                    \
                    Ks[BUF] + 4096 + wv * 1024);                                \
        }

    STAGE(jbeg, 0);
    __syncthreads();
    int buf = 0;

    for (int j0 = jbeg; j0 < jend; j0 += 32) {
        if (j0 + 32 < jend) STAGE(j0 + 32, buf ^ 1);   // prefetch next K tile

        if (j0 <= qmax) {
            // ---- V register prefetch: issue early, consume after softmax ----
            bf16x8 vreg[8];
            #pragma unroll
            for (int dt = 0; dt < 8; ++dt)
                vreg[dt] = *(const bf16x8*)(vbase + (size_t)dt * 16 * T_SEQ + j0);

            const char* ksb = Ks[buf] + kbase;
            const bool fullt = (j0 + 31 <= qmin);      // wave-uniform
            // ---- S^T = K Q : logical-chunk reads, qf[c] pairing ----
            float p[2][4];
            #pragma unroll
            for (int s = 0; s < 2; ++s) {
                if (j0 + s * 16 <= qmax) {
                    f32x4 sa = (f32x4){0.f, 0.f, 0.f, 0.f};
                    __builtin_amdgcn_s_setprio(1);
                    sa = __builtin_amdgcn_mfma_f32_16x16x32_bf16(
                        *(const bf16x8*)(ksb + s * 4096 + koff0), qf[0], sa, 0, 0, 0);
                    sa = __builtin_amdgcn_mfma_f32_16x16x32_bf16(
                        *(const bf16x8*)(ksb + s * 4096 + koff1), qf[1], sa, 0, 0, 0);
                    sa = __builtin_amdgcn_mfma_f32_16x16x32_bf16(
                        *(const bf16x8*)(ksb + s * 4096 + koff2), qf[2], sa, 0, 0, 0);
                    sa = __builtin_amdgcn_mfma_f32_16x16x32_bf16(
                        *(const bf16x8*)(ksb + s * 4096 + koff3), qf[3], sa, 0, 0, 0);
                    __builtin_amdgcn_s_setprio(0);
                    #pragma unroll
                    for (int r = 0; r < 4; ++r) {
                        int key = j0 + s * 16 + lg * 4 + r;
                        p[s][r] = (fullt || key <= tq) ? sa[r] * SCALE2 : -1e30f;
                    }
                } else {
                    #pragma unroll
                    for (int r = 0; r < 4; ++r) p[s][r] = -1e30f;
                }
            }
            // ---- online softmax (log2 domain) with defer-max ----
            float vmax = p[0][0];
            #pragma unroll
            for (int s = 0; s < 2; ++s)
                #pragma unroll
                for (int r = 0; r < 4; ++r) vmax = fmaxf(vmax, p[s][r]);
            vmax = fmaxf(vmax, __shfl_xor(vmax, 16));
            vmax = fmaxf(vmax, __shfl_xor(vmax, 32));
            if (!__all(vmax <= m + THR2)) {
                float mn = fmaxf(m, vmax);
                float rs = vexp2(m - mn);
                m = mn;
                l *= rs;
                float rs_o[4];
                #pragma unroll
                for (int r = 0; r < 4; ++r) rs_o[r] = __shfl(rs, lg * 4 + r);
                #pragma unroll
                for (int dt = 0; dt < 8; ++dt)
                    #pragma unroll
                    for (int r = 0; r < 4; ++r) oacc[dt][r] *= rs_o[r];
            }
            float sum = 0.f;
            #pragma unroll
            for (int s = 0; s < 2; ++s)
                #pragma unroll
                for (int r = 0; r < 4; ++r) {
                    float pe = vexp2(p[s][r] - m);
                    p[s][r] = pe;
                    sum += pe;
                }
            sum += __shfl_xor(sum, 16);
            sum += __shfl_xor(sum, 32);
            l += sum;

            // ---- P -> per-wave LDS via cvt_pk (2 x ds_write_b64) ----
            *(uint2*)pwr0 = make_uint2(cvtpk(p[0][0], p[0][1]), cvtpk(p[0][2], p[0][3]));
            *(uint2*)pwr1 = make_uint2(cvtpk(p[1][0], p[1][1]), cvtpk(p[1][2], p[1][3]));
            asm volatile("" ::: "memory");
            // ---- PV: O += P V (V from registers) ----
            {
                bf16x8 pa = *(const bf16x8*)prd;
                __builtin_amdgcn_s_setprio(1);
                #pragma unroll
                for (int dt = 0; dt < 8; ++dt)
                    oacc[dt] = __builtin_amdgcn_mfma_f32_16x16x32_bf16(pa, vreg[dt], oacc[dt], 0, 0, 0);
                __builtin_amdgcn_s_setprio(0);
            }
        }
        __syncthreads();   // drains K prefetch + guards LDS reuse
        buf ^= 1;
    }

    // ---- write partials (m in log2 domain) ----
    const int p = (hq * 32 + qt) * 5 + seg;
    unsigned short* op = Opart + (size_t)p * 8192;
    #pragma unroll
    for (int r = 0; r < 4; ++r) {
        unsigned short* orow = op + (wv * 16 + lg * 4 + r) * 128;
        #pragma unroll
        for (int dt = 0; dt < 8; ++dt)
            orow[dt * 16 + l15] = f2bf(oacc[dt][r]);
    }
    if (lg == 0) mlpart[p * 64 + wv * 16 + l15] = make_float2(m, l);
    #undef STAGE
}

// ---------------------------------------------------------------------------
// Combine: merge <=4 seq partials + depth partial (slot 4), normalize.
// ---------------------------------------------------------------------------
__global__ __launch_bounds__(256) void attn_combine(
    const unsigned short* __restrict__ Opart, const float2* __restrict__ mlpart,
    unsigned short* __restrict__ AO)
{
    const int bid = blockIdx.x;                 // 512
    const int hq = bid & 15;
    const int qt = bid >> 4;                    // 0..31
    const int nseg = (qt >> 3) + 1;
    const int pbase = (hq * 32 + qt) * 5;
    const int tid = threadIdx.x;
    const int row = tid >> 2;                   // 0..63
    const int dp = tid & 3;                     // 32-d slice
    const int t = qt * 64 + row;

    int slots[5];
    for (int i = 0; i < nseg; ++i) slots[i] = i;
    slots[nseg] = 4;                            // depth partial
    const int cnt = nseg + 1;

    float mi[5], li[5];
    float M = -1e30f;
    for (int i = 0; i < cnt; ++i) {
        float2 v = mlpart[(pbase + slots[i]) * 64 + row];
        mi[i] = v.x; li[i] = v.y;
        M = fmaxf(M, v.x);
    }
    float L = 0.f, w[5];
    for (int i = 0; i < cnt; ++i) {
        w[i] = vexp2(mi[i] - M);
        L += w[i] * li[i];
    }
    float linv = 1.f / L;

    float o[32];
    #pragma unroll
    for (int j = 0; j < 32; ++j) o[j] = 0.f;
    for (int i = 0; i < cnt; ++i) {
        const unsigned short* opr =
            Opart + (size_t)(pbase + slots[i]) * 8192 + row * 128 + dp * 32;
        #pragma unroll
        for (int c = 0; c < 4; ++c) {
            bf16x8 v = *(const bf16x8*)(opr + c * 8);
            #pragma unroll
            for (int j = 0; j < 8; ++j)
                o[c * 8 + j] = fmaf(w[i], bf2f(v[j]), o[c * 8 + j]);
        }
    }
    unsigned short* orow = AO + (size_t)t * DMODEL + hq * HDIM + dp * 32;
    #pragma unroll
    for (int c = 0; c < 4; ++c) {
        bf16x8 v;
        #pragma unroll
        for (int j = 0; j < 8; ++j) v[j] = (short)f2bf(o[c * 8 + j] * linv);
        *(bf16x8*)(orow + c * 8) = v;
    }
}

// ---------------------------------------------------------------------------
extern "C" void kernel_launch(void* const* d_in, const int* in_sizes, int n_in,
                              void* d_out, int out_size, void* d_ws, size_t ws_size,
                              hipStream_t stream) {
    const float* x    = (const float*)d_in[0];
    const float* dk   = (const float*)d_in[1];
    const float* dv   = (const float*)d_in[2];
    const float* cosT = (const float*)d_in[3];
    const float* sinT = (const float*)d_in[4];
    const float* Wq   = (const float*)d_in[5];
    const float* Wk   = (const float*)d_in[6];
    const float* Wv   = (const float*)d_in[7];
    const float* Wo   = (const float*)d_in[8];
    float* out = (float*)d_out;

    // ws (ushort units): xb 4M | Qb 4M | Kb 2M | Vt 2M | WoT 4M | WTp 8M
    // Opart (20.97M) aliases WTp (dead after proj gemm); mlpart after Opart.
    unsigned short* xb  = (unsigned short*)d_ws;
    unsigned short* Qb  = xb + (size_t)4 * 1024 * 1024;
    unsigned short* Kb  = Qb + (size_t)4 * 1024 * 1024;
    unsigned short* Vt  = Kb + (size_t)2 * 1024 * 1024;
    unsigned short* WoT = Vt + (size_t)2 * 1024 * 1024;
    unsigned short* WTp = WoT + (size_t)4 * 1024 * 1024;
    unsigned short* Opart = WTp;                      // alias (WTp dead post-proj)
    float2* mlpart = (float2*)(Opart + (size_t)2560 * 8192);
    unsigned short* AOb = xb;                         // alias (xb dead post-proj)

    prep<<<dim3(5120), 256, 0, stream>>>(x, Wq, Wk, Wv, Wo, xb, WTp, WoT);
    gemm_bt<<<dim3(64, 16), 256, 0, stream>>>(xb, WTp, nullptr, Qb, Kb, Vt, 1, DMODEL);
    rope2<<<dim3(12288), 256, 0, stream>>>(Qb, Kb, cosT, sinT);
    attn_fused<<<dim3(1792), 256, 0, stream>>>(Qb, Kb, Vt, dk, dv, Opart, mlpart);
    attn_combine<<<dim3(512), 256, 0, stream>>>(Opart, mlpart, AOb);
    gemm_bt64<<<dim3(32, 32), 256, 0, stream>>>(AOb, WoT, out, DMODEL);
}

// Round 18
// 156.413 us; speedup vs baseline: 1.8869x; 1.8869x over previous
//
#include <hip/hip_runtime.h>
#include <hip/hip_bf16.h>
#include <math.h>

#define T_SEQ 2048
#define DMODEL 2048
#define NHQ 16
#define NHK 8
#define HDIM 128
#define NL 4
#define ATT_SCALE 0.08838834764831845f   // 1/sqrt(128)
#define SCALE2 0.12751649736383447f      // ATT_SCALE * log2(e)
#define THR2 11.541560327111707f         // 8 * log2(e)

typedef __attribute__((ext_vector_type(8))) short bf16x8;
typedef __attribute__((ext_vector_type(4))) float f32x4;

__device__ __forceinline__ float bf2f(short u) {
    union { float f; unsigned int i; } x;
    x.i = ((unsigned int)(unsigned short)u) << 16;
    return x.f;
}
__device__ __forceinline__ unsigned short f2bf(float f) {
    __hip_bfloat16 h = __float2bfloat16(f);
    return *reinterpret_cast<unsigned short*>(&h);
}
__device__ __forceinline__ float vexp2(float x) {      // 2^x, 1 inst
    float r;
    asm("v_exp_f32 %0, %1" : "=v"(r) : "v"(x));
    return r;
}
__device__ __forceinline__ unsigned int cvtpk(float lo, float hi) {  // lo->b16[0], hi->b16[1]
    unsigned int r;
    asm("v_cvt_pk_bf16_f32 %0, %1, %2" : "=v"(r) : "v"(lo), "v"(hi));
    return r;
}
__device__ __forceinline__ void gload16(const void* g, void* l) {
    __builtin_amdgcn_global_load_lds(
        (const __attribute__((address_space(1))) void*)g,
        (__attribute__((address_space(3))) void*)l, 16, 0, 0);
}

// ---------------------------------------------------------------------------
// Fused prep: x cast (blocks 0..2047) + 4 weight transpose-casts.
// ---------------------------------------------------------------------------
__global__ __launch_bounds__(256) void prep(
    const float* __restrict__ x, const float* __restrict__ Wq,
    const float* __restrict__ Wk, const float* __restrict__ Wv,
    const float* __restrict__ Wo,
    unsigned short* __restrict__ xb, unsigned short* __restrict__ WTp,
    unsigned short* __restrict__ WoT)
{
    __shared__ float ls[64][65];
    const int bid = blockIdx.x, tid = threadIdx.x;
    if (bid < 2048) {                      // ---- x cast ----
        int i = bid * 256 + tid;
        float4 a = ((const float4*)x)[2 * i];
        float4 b = ((const float4*)x)[2 * i + 1];
        bf16x8 v;
        v[0] = (short)f2bf(a.x); v[1] = (short)f2bf(a.y);
        v[2] = (short)f2bf(a.z); v[3] = (short)f2bf(a.w);
        v[4] = (short)f2bf(b.x); v[5] = (short)f2bf(b.y);
        v[6] = (short)f2bf(b.z); v[7] = (short)f2bf(b.w);
        ((bf16x8*)xb)[i] = v;
        return;
    }
    int v = bid - 2048;
    const float* src; unsigned short* dst; int Nsrc, dstOff, id;
    if (v < 1024)      { src = Wq; dst = WTp; Nsrc = 2048; dstOff = 0;    id = v; }
    else if (v < 1536) { src = Wk; dst = WTp; Nsrc = 1024; dstOff = 2048; id = v - 1024; }
    else if (v < 2048) { src = Wv; dst = WTp; Nsrc = 1024; dstOff = 3072; id = v - 1536; }
    else               { src = Wo; dst = WoT; Nsrc = 2048; dstOff = 0;    id = v - 2048; }
    const int k0 = (id & 31) * 64, n0 = (id >> 5) * 64;
    #pragma unroll
    for (int it = 0; it < 4; ++it) {
        int fi = tid + it * 256;
        int r = fi >> 4;
        int c = (fi & 15) * 4;
        float4 w = *(const float4*)&src[(size_t)(k0 + r) * Nsrc + n0 + c];
        ls[r][c] = w.x; ls[r][c + 1] = w.y; ls[r][c + 2] = w.z; ls[r][c + 3] = w.w;
    }
    __syncthreads();
    int n = tid & 63, kc = tid >> 6;
    bf16x8 v0, v1;
    #pragma unroll
    for (int j = 0; j < 8; ++j) v0[j] = (short)f2bf(ls[kc * 16 + j][n]);
    #pragma unroll
    for (int j = 0; j < 8; ++j) v1[j] = (short)f2bf(ls[kc * 16 + 8 + j][n]);
    size_t drow = (size_t)(dstOff + n0 + n) * 2048 + k0 + kc * 16;
    *(bf16x8*)&dst[drow] = v0;
    *(bf16x8*)&dst[drow + 8] = v1;
}

// ---------------------------------------------------------------------------
// bf16 MFMA GEMM, 128x64 tile (validated R8). mode 1: fused proj epilogue.
// ---------------------------------------------------------------------------
__global__ __launch_bounds__(256, 4) void gemm_bt(
    const unsigned short* __restrict__ A, const unsigned short* __restrict__ Bt,
    float* __restrict__ Cf, unsigned short* __restrict__ Cq,
    unsigned short* __restrict__ Ck, unsigned short* __restrict__ Cv,
    int mode, int K)
{
    __shared__ char As[16384];   // [128 m][64 k] bf16, chunk ^= row&7
    __shared__ char Bs[8192];    // [64 n][64 k] bf16, chunk ^= row&7
    const int tid = threadIdx.x;
    const int wv = tid >> 6, lane = tid & 63;
    const int l15 = lane & 15, lg = lane >> 4;
    const int wm = wv >> 1, wn = wv & 1;
    const int bm = blockIdx.y * 128, bn = blockIdx.x * 64;

    f32x4 acc[4][2];
    #pragma unroll
    for (int i = 0; i < 4; ++i)
        #pragma unroll
        for (int j = 0; j < 2; ++j)
            acc[i][j] = (f32x4){0.f, 0.f, 0.f, 0.f};

    for (int k0 = 0; k0 < K; k0 += 64) {
        #pragma unroll
        for (int it = 0; it < 4; ++it) {
            int o = it * 4096 + tid * 16;
            int row = o >> 7;
            int sch = ((o >> 4) & 7) ^ (row & 7);
            gload16((const char*)A + ((((size_t)(bm + row) * K) + k0 + sch * 8) << 1),
                    As + it * 4096 + wv * 1024);
        }
        #pragma unroll
        for (int it = 0; it < 2; ++it) {
            int o = it * 4096 + tid * 16;
            int row = o >> 7;
            int sch = ((o >> 4) & 7) ^ (row & 7);
            gload16((const char*)Bt + ((((size_t)(bn + row) * K) + k0 + sch * 8) << 1),
                    Bs + it * 4096 + wv * 1024);
        }
        __syncthreads();
        #pragma unroll
        for (int kk = 0; kk < 2; ++kk) {
            bf16x8 av[4], bv[2];
            #pragma unroll
            for (int f = 0; f < 4; ++f) {
                int ra = wm * 64 + f * 16 + l15;
                av[f] = *(const bf16x8*)(As + ra * 128 + ((((kk << 2) | lg) ^ (ra & 7)) << 4));
            }
            #pragma unroll
            for (int f = 0; f < 2; ++f) {
                int rb = wn * 32 + f * 16 + l15;
                bv[f] = *(const bf16x8*)(Bs + rb * 128 + ((((kk << 2) | lg) ^ (rb & 7)) << 4));
            }
            #pragma unroll
            for (int mf = 0; mf < 4; ++mf)
                #pragma unroll
                for (int nf = 0; nf < 2; ++nf)
                    acc[mf][nf] = __builtin_amdgcn_mfma_f32_16x16x32_bf16(
                        av[mf], bv[nf], acc[mf][nf], 0, 0, 0);
        }
        __syncthreads();
    }

    #pragma unroll
    for (int mf = 0; mf < 4; ++mf) {
        int m0 = bm + wm * 64 + mf * 16 + lg * 4;
        #pragma unroll
        for (int nf = 0; nf < 2; ++nf) {
            int n0 = bn + wn * 32 + nf * 16 + l15;
            if (mode == 0) {
                #pragma unroll
                for (int r = 0; r < 4; ++r)
                    Cf[(size_t)(m0 + r) * 2048 + n0] = acc[mf][nf][r];
            } else if (n0 < 2048) {
                #pragma unroll
                for (int r = 0; r < 4; ++r)
                    Cq[(size_t)(m0 + r) * 2048 + n0] = f2bf(acc[mf][nf][r]);
            } else if (n0 < 3072) {
                #pragma unroll
                for (int r = 0; r < 4; ++r)
                    Ck[(size_t)(m0 + r) * 1024 + (n0 - 2048)] = f2bf(acc[mf][nf][r]);
            } else {
                ushort4 u;
                u.x = f2bf(acc[mf][nf][0]); u.y = f2bf(acc[mf][nf][1]);
                u.z = f2bf(acc[mf][nf][2]); u.w = f2bf(acc[mf][nf][3]);
                *(ushort4*)&Cv[(size_t)(n0 - 3072) * 2048 + m0] = u;
            }
        }
    }
}

// ---------------------------------------------------------------------------
// bf16 MFMA GEMM, 64x64 tile, f32 C (Wo: grid 32x32 = 4 blocks/CU).
// ---------------------------------------------------------------------------
__global__ __launch_bounds__(256, 4) void gemm_bt64(
    const unsigned short* __restrict__ A, const unsigned short* __restrict__ Bt,
    float* __restrict__ Cf, int K)
{
    __shared__ char As[8192];    // [64 m][64 k] bf16, chunk ^= row&7
    __shared__ char Bs[8192];    // [64 n][64 k] bf16, chunk ^= row&7
    const int tid = threadIdx.x;
    const int wv = tid >> 6, lane = tid & 63;
    const int l15 = lane & 15, lg = lane >> 4;
    const int wm = wv >> 1, wn = wv & 1;
    const int bm = blockIdx.y * 64, bn = blockIdx.x * 64;

    f32x4 acc[2][2];
    #pragma unroll
    for (int i = 0; i < 2; ++i)
        #pragma unroll
        for (int j = 0; j < 2; ++j)
            acc[i][j] = (f32x4){0.f, 0.f, 0.f, 0.f};

    for (int k0 = 0; k0 < K; k0 += 64) {
        #pragma unroll
        for (int it = 0; it < 2; ++it) {
            int o = it * 4096 + tid * 16;
            int row = o >> 7;
            int sch = ((o >> 4) & 7) ^ (row & 7);
            gload16((const char*)A + ((((size_t)(bm + row) * K) + k0 + sch * 8) << 1),
                    As + it * 4096 + wv * 1024);
            gload16((const char*)Bt + ((((size_t)(bn + row) * K) + k0 + sch * 8) << 1),
                    Bs + it * 4096 + wv * 1024);
        }
        __syncthreads();
        #pragma unroll
        for (int kk = 0; kk < 2; ++kk) {
            bf16x8 av[2], bv[2];
            #pragma unroll
            for (int f = 0; f < 2; ++f) {
                int ra = wm * 32 + f * 16 + l15;
                av[f] = *(const bf16x8*)(As + ra * 128 + ((((kk << 2) | lg) ^ (ra & 7)) << 4));
                int rb = wn * 32 + f * 16 + l15;
                bv[f] = *(const bf16x8*)(Bs + rb * 128 + ((((kk << 2) | lg) ^ (rb & 7)) << 4));
            }
            #pragma unroll
            for (int mf = 0; mf < 2; ++mf)
                #pragma unroll
                for (int nf = 0; nf < 2; ++nf)
                    acc[mf][nf] = __builtin_amdgcn_mfma_f32_16x16x32_bf16(
                        av[mf], bv[nf], acc[mf][nf], 0, 0, 0);
        }
        __syncthreads();
    }

    #pragma unroll
    for (int mf = 0; mf < 2; ++mf) {
        int m0 = bm + wm * 32 + mf * 16 + lg * 4;
        #pragma unroll
        for (int nf = 0; nf < 2; ++nf) {
            int n0 = bn + wn * 32 + nf * 16 + l15;
            #pragma unroll
            for (int r = 0; r < 4; ++r)
                Cf[(size_t)(m0 + r) * 2048 + n0] = acc[mf][nf][r];
        }
    }
}

// ---------------------------------------------------------------------------
// Fused RoPE on Qb (H=16) and Kb (H=8), one dispatch.
// ---------------------------------------------------------------------------
__global__ __launch_bounds__(256) void rope2(
    unsigned short* __restrict__ Qb, unsigned short* __restrict__ Kb,
    const float* __restrict__ cosT, const float* __restrict__ sinT)
{
    int idx = blockIdx.x * 256 + threadIdx.x;
    unsigned short* P; int H;
    if (idx < T_SEQ * NHQ * 64) { P = Qb; H = NHQ; }
    else { idx -= T_SEQ * NHQ * 64; P = Kb; H = NHK; }
    int d = idx & 63;
    int h = (idx >> 6) % H;
    int t = idx / (64 * H);
    float c = cosT[t * HDIM + d];
    float s = sinT[t * HDIM + d];
    unsigned short* row = P + (size_t)t * (H * HDIM) + h * HDIM;
    float x0 = bf2f((short)row[d]), x1 = bf2f((short)row[d + 64]);
    row[d]      = f2bf(x0 * c - x1 * s);
    row[d + 64] = f2bf(x1 * c + x0 * s);
}

// ---------------------------------------------------------------------------
// Fused attention (R16-verified, best: attn ~63us). Depth blocks interleaved
// among seq blocks in groups of 8 (one per XCD): group g of 224, depth iff
// g%7<2 (512 blocks), seq otherwise (1280 blocks). K/V LDS-staged dbuf with
// prefetch-before-compute; packed cvt_pk P-LDS transpose; exp2-domain
// softmax with defer-max; hoisted lane-constant addressing; XCD pinning.
// ---------------------------------------------------------------------------
__global__ __launch_bounds__(256, 4) void attn_fused(
    const unsigned short* __restrict__ Qb, const unsigned short* __restrict__ Kb,
    const unsigned short* __restrict__ Vt,
    const float* __restrict__ Dk, const float* __restrict__ Dv,
    unsigned short* __restrict__ Opart, float2* __restrict__ mlpart)
{
    __shared__ char Ks[2][8192];   // [32 keys][128 d] bf16, chunk ^= key&7
    __shared__ char Vs[2][8192];   // [128 d][32 keys] bf16, chunk ^= (d>>1)&3
    __shared__ char Ps[4096];      // 4 waves x [16 q][32 keys] bf16

    const int bid0 = blockIdx.x;
    const int tid = threadIdx.x;
    const size_t DSTRIDE = (size_t)NHK * T_SEQ * HDIM;

    const int grp = bid0 >> 3, xcd = bid0 & 7;
    const int gm = grp % 7, gd = grp / 7;

    if (gm < 2) {
        // ================= depth partials (slot 4), interleaved =================
        const int hk = xcd;
        const int tc = gd * 2 + gm;             // 0..63
        const int row = tid >> 3;               // 0..31
        const int dp = tid & 7;                 // 16-d slice
        const int t = tc * 32 + row;
        const int qt = t >> 6, rowin = t & 63;
        const size_t base = ((size_t)hk * T_SEQ + t) * HDIM + dp * 16;

        float q[2][16];
        #pragma unroll
        for (int e = 0; e < 2; ++e) {
            const unsigned short* qp = Qb + (size_t)t * DMODEL + (hk * 2 + e) * HDIM + dp * 16;
            bf16x8 v0 = *(const bf16x8*)qp;
            bf16x8 v1 = *(const bf16x8*)(qp + 8);
            #pragma unroll
            for (int j = 0; j < 8; ++j) { q[e][j] = bf2f(v0[j]); q[e][8 + j] = bf2f(v1[j]); }
        }
        float dl[2][NL];
        #pragma unroll
        for (int l = 0; l < NL; ++l) {
            const float* kp = Dk + l * DSTRIDE + base;
            float a0 = 0.f, a1 = 0.f;
            #pragma unroll
            for (int c = 0; c < 4; ++c) {
                float4 k4 = *(const float4*)(kp + c * 4);
                a0 = fmaf(q[0][c*4+0], k4.x, a0); a0 = fmaf(q[0][c*4+1], k4.y, a0);
                a0 = fmaf(q[0][c*4+2], k4.z, a0); a0 = fmaf(q[0][c*4+3], k4.w, a0);
                a1 = fmaf(q[1][c*4+0], k4.x, a1); a1 = fmaf(q[1][c*4+1], k4.y, a1);
                a1 = fmaf(q[1][c*4+2], k4.z, a1); a1 = fmaf(q[1][c*4+3], k4.w, a1);
            }
            a0 += __shfl_xor(a0, 1); a0 += __shfl_xor(a0, 2); a0 += __shfl_xor(a0, 4);
            a1 += __shfl_xor(a1, 1); a1 += __shfl_xor(a1, 2); a1 += __shfl_xor(a1, 4);
            dl[0][l] = a0 * SCALE2;              // log2 domain
            dl[1][l] = a1 * SCALE2;
        }
        float m2[2], ls2[2], pd[2][NL];
        #pragma unroll
        for (int e = 0; e < 2; ++e) {
            m2[e] = fmaxf(fmaxf(dl[e][0], dl[e][1]), fmaxf(dl[e][2], dl[e][3]));
            ls2[e] = 0.f;
            #pragma unroll
            for (int l = 0; l < NL; ++l) { pd[e][l] = vexp2(dl[e][l] - m2[e]); ls2[e] += pd[e][l]; }
        }
        float o[2][16];
        #pragma unroll
        for (int e = 0; e < 2; ++e)
            #pragma unroll
            for (int j = 0; j < 16; ++j) o[e][j] = 0.f;
        #pragma unroll
        for (int l = 0; l < NL; ++l) {
            const float* vp = Dv + l * DSTRIDE + base;
            #pragma unroll
            for (int c = 0; c < 4; ++c) {
                float4 v4 = *(const float4*)(vp + c * 4);
                #pragma unroll
                for (int e = 0; e < 2; ++e) {
                    o[e][c*4+0] = fmaf(pd[e][l], v4.x, o[e][c*4+0]);
                    o[e][c*4+1] = fmaf(pd[e][l], v4.y, o[e][c*4+1]);
                    o[e][c*4+2] = fmaf(pd[e][l], v4.z, o[e][c*4+2]);
                    o[e][c*4+3] = fmaf(pd[e][l], v4.w, o[e][c*4+3]);
                }
            }
        }
        #pragma unroll
        for (int e = 0; e < 2; ++e) {
            int pidx = ((hk * 2 + e) * 32 + qt) * 5 + 4;
            unsigned short* dst = Opart + (size_t)pidx * 8192 + rowin * 128 + dp * 16;
            bf16x8 w0, w1;
            #pragma unroll
            for (int j = 0; j < 8; ++j) { w0[j] = (short)f2bf(o[e][j]); w1[j] = (short)f2bf(o[e][8 + j]); }
            *(bf16x8*)dst = w0;
            *(bf16x8*)(dst + 8) = w1;
            if (dp == 0) mlpart[pidx * 64 + rowin] = make_float2(m2[e], ls2[e]);
        }
        return;
    }

    // ================= seq split-K attention (interleaved) =================
    const int hk = xcd;
    const int idx = gd * 5 + (gm - 2);            // 0..159, rises with dispatch
    const int hq = hk * 2 + (idx & 1);
    const int si = 79 - (idx >> 1);               // long segments first
    int qt, seg;
    if (si < 8)       { qt = si;            seg = 0; }
    else if (si < 24) { int v = si - 8;  qt = 8  + (v >> 1); seg = v & 1; }
    else if (si < 48) { int v = si - 24; int q3 = v / 3; qt = 16 + q3; seg = v - q3 * 3; }
    else              { int v = si - 48; qt = 24 + (v >> 2); seg = v & 3; }
    const int q0 = qt * 64;
    const int jbeg = seg * 512;
    const int jend = min(jbeg + 512, q0 + 64);

    const int wv = tid >> 6, lane = tid & 63;
    const int l15 = lane & 15, lg = lane >> 4;

    const int tq = q0 + wv * 16 + l15;
    const int qmax = q0 + wv * 16 + 15;
    const int qmin = q0 + wv * 16;

    bf16x8 qf[4];
    {
        const unsigned short* qrow = Qb + (size_t)tq * DMODEL + hq * HDIM;
        #pragma unroll
        for (int c = 0; c < 4; ++c)
            qf[c] = *(const bf16x8*)(qrow + c * 32 + lg * 8);
    }

    // ---- hoisted lane-constant addressing ----
    const int kx = l15 & 7;
    const int koff0 = ((lg + 0)  ^ kx) << 4;
    const int koff1 = ((lg + 4)  ^ kx) << 4;
    const int koff2 = ((lg + 8)  ^ kx) << 4;
    const int koff3 = ((lg + 12) ^ kx) << 4;
    const int kbase = l15 * 256;
    const int w2  = (l15 >> 1) & 3;
    const int vbaseV = l15 * 64 + ((lg ^ w2) << 4);
    char* pw = Ps + wv * 1024;
    char* pwr0 = pw + l15 * 64 + (((lg >> 1) ^ w2) << 4) + (lg & 1) * 8;
    char* pwr1 = pw + l15 * 64 + ((((lg >> 1) + 2) ^ w2) << 4) + (lg & 1) * 8;
    const char* prd = pw + l15 * 64 + ((lg ^ w2) << 4);

    const int rk = tid >> 4, ckk = tid & 15;
    const size_t kc0 = (size_t)rk * 2048 + hk * 256 + ((size_t)(ckk ^ (rk & 7)) << 4);
    const int rv = tid >> 2, cvv = tid & 3;
    const size_t vc0 = ((size_t)(hk * 128 + rv)) * 4096 + ((size_t)(cvv ^ ((rv >> 1) & 3)) << 4);
    const char* KbB = (const char*)Kb;
    const char* VtB = (const char*)Vt;

    f32x4 oacc[8];
    #pragma unroll
    for (int dt = 0; dt < 8; ++dt) oacc[dt] = (f32x4){0.f, 0.f, 0.f, 0.f};
    float m = -1e30f, l = 0.f;               // m in log2 domain

    #define STAGE(J0, BUF)                                                      \
        {                                                                       \
            gload16(KbB + (size_t)(J0) * 2048 + kc0, Ks[BUF] + wv * 1024);      \
            gload16(KbB + (size_t)(J0) * 2048 + kc0 + 32768,                    \
                    Ks[BUF] + 4096 + wv * 1024);                                \
            gload16(VtB + (size_t)(J0) * 2 + vc0, Vs[BUF] + wv * 1024);         \
            gload16(VtB + (size_t)(J0) * 2 + vc0 + 262144,                      \
                    Vs[BUF] + 4096 + wv * 1024);                                \
        }

    STAGE(jbeg, 0);
    __syncthreads();
    int buf = 0;

    for (int j0 = jbeg; j0 < jend; j0 += 32) {
        if (j0 + 32 < jend) STAGE(j0 + 32, buf ^ 1);   // prefetch next tile

        if (j0 <= qmax) {
            const char* ksb = Ks[buf] + kbase;
            const char* vsb = Vs[buf] + vbaseV;
            const bool fullt = (j0 + 31 <= qmin);      // wave-uniform
            // ---- S^T = K Q : logical-chunk reads, qf[c] pairing ----
            float p[2][4];
            #pragma unroll
            for (int s = 0; s < 2; ++s) {
                if (j0 + s * 16 <= qmax) {
                    f32x4 sa = (f32x4){0.f, 0.f, 0.f, 0.f};
                    __builtin_amdgcn_s_setprio(1);
                    sa = __builtin_amdgcn_mfma_f32_16x16x32_bf16(
                        *(const bf16x8*)(ksb + s * 4096 + koff0), qf[0], sa, 0, 0, 0);
                    sa = __builtin_amdgcn_mfma_f32_16x16x32_bf16(
                        *(const bf16x8*)(ksb + s * 4096 + koff1), qf[1], sa, 0, 0, 0);
                    sa = __builtin_amdgcn_mfma_f32_16x16x32_bf16(
                        *(const bf16x8*)(ksb + s * 4096 + koff2), qf[2], sa, 0, 0, 0);
                    sa = __builtin_amdgcn_mfma_f32_16x16x32_bf16(
                        *(const bf16x8*)(ksb + s * 4096 + koff3), qf[3], sa, 0, 0, 0);
                    __builtin_amdgcn_s_setprio(0);
                    #pragma unroll
                    for (int r = 0; r < 4; ++r) {
                        int key = j0 + s * 16 + lg * 4 + r;
                        p[s][r] = (fullt || key <= tq) ? sa[r] * SCALE2 : -1e30f;
                    }
                } else {
                    #pragma unroll
                    for (int r = 0; r < 4; ++r) p[s][r] = -1e30f;
                }
            }
            // ---- online softmax (log2 domain) with defer-max ----
            float vmax = p[0][0];
            #pragma unroll
            for (int s = 0; s < 2; ++s)
                #pragma unroll
                for (int r = 0; r < 4; ++r) vmax = fmaxf(vmax, p[s][r]);
            vmax = fmaxf(vmax, __shfl_xor(vmax, 16));
            vmax = fmaxf(vmax, __shfl_xor(vmax, 32));
            if (!__all(vmax <= m + THR2)) {
                float mn = fmaxf(m, vmax);
                float rs = vexp2(m - mn);
                m = mn;
                l *= rs;
                float rs_o[4];
                #pragma unroll
                for (int r = 0; r < 4; ++r) rs_o[r] = __shfl(rs, lg * 4 + r);
                #pragma unroll
                for (int dt = 0; dt < 8; ++dt)
                    #pragma unroll
                    for (int r = 0; r < 4; ++r) oacc[dt][r] *= rs_o[r];
            }
            float sum = 0.f;
            #pragma unroll
            for (int s = 0; s < 2; ++s)
                #pragma unroll
                for (int r = 0; r < 4; ++r) {
                    float pe = vexp2(p[s][r] - m);
                    p[s][r] = pe;
                    sum += pe;
                }
            sum += __shfl_xor(sum, 16);
            sum += __shfl_xor(sum, 32);
            l += sum;

            // ---- P -> per-wave LDS via cvt_pk (2 x ds_write_b64) ----
            *(uint2*)pwr0 = make_uint2(cvtpk(p[0][0], p[0][1]), cvtpk(p[0][2], p[0][3]));
            *(uint2*)pwr1 = make_uint2(cvtpk(p[1][0], p[1][1]), cvtpk(p[1][2], p[1][3]));
            asm volatile("" ::: "memory");
            // ---- PV: O += P V (imm-offset V reads) ----
            {
                bf16x8 pa = *(const bf16x8*)prd;
                __builtin_amdgcn_s_setprio(1);
                #pragma unroll
                for (int dt = 0; dt < 8; ++dt) {
                    bf16x8 vf = *(const bf16x8*)(vsb + dt * 1024);
                    oacc[dt] = __builtin_amdgcn_mfma_f32_16x16x32_bf16(pa, vf, oacc[dt], 0, 0, 0);
                }
                __builtin_amdgcn_s_setprio(0);
            }
        }
        __syncthreads();   // drains prefetch + guards LDS reuse
        buf ^= 1;
    }

    // ---- write partials (m in log2 domain) ----
    const int p = (hq * 32 + qt) * 5 + seg;
    unsigned short* op = Opart + (size_t)p * 8192;
    #pragma unroll
    for (int r = 0; r < 4; ++r) {
        unsigned short* orow = op + (wv * 16 + lg * 4 + r) * 128;
        #pragma unroll
        for (int dt = 0; dt < 8; ++dt)
            orow[dt * 16 + l15] = f2bf(oacc[dt][r]);
    }
    if (lg == 0) mlpart[p * 64 + wv * 16 + l15] = make_float2(m, l);
    #undef STAGE
}

// ---------------------------------------------------------------------------
// Combine: merge <=4 seq partials + depth partial (slot 4), normalize.
// ---------------------------------------------------------------------------
__global__ __launch_bounds__(256) void attn_combine(
    const unsigned short* __restrict__ Opart, const float2* __restrict__ mlpart,
    unsigned short* __restrict__ AO)
{
    const int bid = blockIdx.x;                 // 512
    const int hq = bid & 15;
    const int qt = bid >> 4;                    // 0..31
    const int nseg = (qt >> 3) + 1;
    const int pbase = (hq * 32 + qt) * 5;
    const int tid = threadIdx.x;
    const int row = tid >> 2;                   // 0..63
    const int dp = tid & 3;                     // 32-d slice
    const int t = qt * 64 + row;

    int slots[5];
    for (int i = 0; i < nseg; ++i) slots[i] = i;
    slots[nseg] = 4;                            // depth partial
    const int cnt = nseg + 1;

    float mi[5], li[5];
    float M = -1e30f;
    for (int i = 0; i < cnt; ++i) {
        float2 v = mlpart[(pbase + slots[i]) * 64 + row];
        mi[i] = v.x; li[i] = v.y;
        M = fmaxf(M, v.x);
    }
    float L = 0.f, w[5];
    for (int i = 0; i < cnt; ++i) {
        w[i] = vexp2(mi[i] - M);
        L += w[i] * li[i];
    }
    float linv = 1.f / L;

    float o[32];
    #pragma unroll
    for (int j = 0; j < 32; ++j) o[j] = 0.f;
    for (int i = 0; i < cnt; ++i) {
        const unsigned short* opr =
            Opart + (size_t)(pbase + slots[i]) * 8192 + row * 128 + dp * 32;
        #pragma unroll
        for (int c = 0; c < 4; ++c) {
            bf16x8 v = *(const bf16x8*)(opr + c * 8);
            #pragma unroll
            for (int j = 0; j < 8; ++j)
                o[c * 8 + j] = fmaf(w[i], bf2f(v[j]), o[c * 8 + j]);
        }
    }
    unsigned short* orow = AO + (size_t)t * DMODEL + hq * HDIM + dp * 32;
    #pragma unroll
    for (int c = 0; c < 4; ++c) {
        bf16x8 v;
        #pragma unroll
        for (int j = 0; j < 8; ++j) v[j] = (short)f2bf(o[c * 8 + j] * linv);
        *(bf16x8*)(orow + c * 8) = v;
    }
}

// ---------------------------------------------------------------------------
extern "C" void kernel_launch(void* const* d_in, const int* in_sizes, int n_in,
                              void* d_out, int out_size, void* d_ws, size_t ws_size,
                              hipStream_t stream) {
    const float* x    = (const float*)d_in[0];
    const float* dk   = (const float*)d_in[1];
    const float* dv   = (const float*)d_in[2];
    const float* cosT = (const float*)d_in[3];
    const float* sinT = (const float*)d_in[4];
    const float* Wq   = (const float*)d_in[5];
    const float* Wk   = (const float*)d_in[6];
    const float* Wv   = (const float*)d_in[7];
    const float* Wo   = (const float*)d_in[8];
    float* out = (float*)d_out;

    // ws (ushort units): xb 4M | Qb 4M | Kb 2M | Vt 2M | WoT 4M | WTp 8M
    // Opart (20.97M) aliases WTp (dead after proj gemm); mlpart after Opart.
    unsigned short* xb  = (unsigned short*)d_ws;
    unsigned short* Qb  = xb + (size_t)4 * 1024 * 1024;
    unsigned short* Kb  = Qb + (size_t)4 * 1024 * 1024;
    unsigned short* Vt  = Kb + (size_t)2 * 1024 * 1024;
    unsigned short* WoT = Vt + (size_t)2 * 1024 * 1024;
    unsigned short* WTp = WoT + (size_t)4 * 1024 * 1024;
    unsigned short* Opart = WTp;                      // alias (WTp dead post-proj)
    float2* mlpart = (float2*)(Opart + (size_t)2560 * 8192);
    unsigned short* AOb = xb;                         // alias (xb dead post-proj)

    prep<<<dim3(5120), 256, 0, stream>>>(x, Wq, Wk, Wv, Wo, xb, WTp, WoT);
    gemm_bt<<<dim3(64, 16), 256, 0, stream>>>(xb, WTp, nullptr, Qb, Kb, Vt, 1, DMODEL);
    rope2<<<dim3(12288), 256, 0, stream>>>(Qb, Kb, cosT, sinT);
    attn_fused<<<dim3(1792), 256, 0, stream>>>(Qb, Kb, Vt, dk, dv, Opart, mlpart);
    attn_combine<<<dim3(512), 256, 0, stream>>>(Opart, mlpart, AOb);
    gemm_bt64<<<dim3(32, 32), 256, 0, stream>>>(AOb, WoT, out, DMODEL);
}